// Round 7
// baseline (3436.320 us; speedup 1.0000x reference)
//
#include <hip/hip_runtime.h>
#include <math.h>

// ---------------------------------------------------------------------------
// PhysicalMoE — routed (top-2) MoE.
// Fast path (ws >= ~325 MB): pre-convert x/W1/W2 to bf16 hi/lo planes
// (weights transposed to [n][k]) -> MFMA split-bf16 GEMMs (err ~2^-15, i.e.
// fp32-equivalent) with global_load_lds staging + XOR swizzle via per-lane
// global source addresses (LDS linear).
// Fallback path (small ws): round-0 fp32 VALU GEMMs.
// R6 hardening: every launch gated on ws_size covering what it writes.
// A too-small ws now yields clean zero output (diagnosable) instead of a
// GPU page fault that can kill the container ("container failed twice").
// ---------------------------------------------------------------------------

#define B_TOK 16384
#define IN_D 1024
#define HID_D 4096
#define OUT_D 1024
#define NEXP 8
#define SIG_D 32
#define RIN 1059

#define TILE 128
#define BK 16  // fp32 fallback k-step
#define ROWS_MAX 33792

#define CTRL_COUNTS 0
#define CTRL_CURS 8
#define CTRL_OFFS 16

typedef float f32x4 __attribute__((ext_vector_type(4)));
typedef short s16x8 __attribute__((ext_vector_type(8)));

__device__ __forceinline__ float gelu_exact(float v) {
    return 0.5f * v * (1.0f + erff(v * 0.70710678118654752440f));
}

__device__ __forceinline__ unsigned short rtne_bf16(float f) {
    unsigned u = __float_as_uint(f);
    unsigned r = u + 0x7FFFu + ((u >> 16) & 1u);
    return (unsigned short)(r >> 16);
}
__device__ __forceinline__ float bf16f(unsigned short h) {
    return __uint_as_float(((unsigned)h) << 16);
}
__device__ __forceinline__ void split2(float f, unsigned short& h, unsigned short& lo) {
    h = rtne_bf16(f);
    lo = rtne_bf16(f - bf16f(h));
}

// global -> LDS direct (16B/lane). lds base is wave-uniform; HW scatters lane i
// at base + i*16. Global src is per-lane (carries the XOR swizzle).
__device__ __forceinline__ void gl16(const unsigned short* g, unsigned short* lds) {
    __builtin_amdgcn_global_load_lds(
        (const __attribute__((address_space(1))) void*)g,
        (__attribute__((address_space(3))) void*)lds, 16, 0, 0);
}

// ---------------- control / routing (unchanged from round 0) ----------------

__global__ void zero_ctrl_kernel(int* ctrl) {
    if (threadIdx.x < 32) ctrl[threadIdx.x] = 0;
}

__global__ void zero_out_kernel(float4* out, int n4) {
    int i = blockIdx.x * blockDim.x + threadIdx.x;
    int stride = gridDim.x * blockDim.x;
    for (; i < n4; i += stride) out[i] = make_float4(0.f, 0.f, 0.f, 0.f);
}

__global__ __launch_bounds__(256)
void router_kernel(const float* __restrict__ x, const float* __restrict__ sig,
                   const float* __restrict__ tc, const float* __restrict__ rs,
                   const float* __restrict__ rw1, const float* __restrict__ rb1,
                   const float* __restrict__ rw2, const float* __restrict__ rb2,
                   int* __restrict__ ctrl, int* __restrict__ tt_idx,
                   float2* __restrict__ tt_w) {
    const int wave = threadIdx.x >> 6;
    const int lane = threadIdx.x & 63;
    const int t = blockIdx.x * 4 + wave;

    float acc[16];
#pragma unroll
    for (int j = 0; j < 16; ++j) acc[j] = 0.f;

    for (int i = lane; i < RIN; i += 64) {
        float xv;
        if (i < IN_D) xv = x[(size_t)t * IN_D + i];
        else if (i < IN_D + SIG_D) xv = sig[(size_t)t * SIG_D + (i - IN_D)];
        else if (i == IN_D + SIG_D) xv = tc[t];
        else xv = rs[(size_t)t * 2 + (i - (IN_D + SIG_D + 1))];
        const float4* wr = (const float4*)(rw1 + (size_t)i * 16);
        float4 wa = wr[0], wb = wr[1], wc = wr[2], wd = wr[3];
        acc[0]  = fmaf(xv, wa.x, acc[0]);  acc[1]  = fmaf(xv, wa.y, acc[1]);
        acc[2]  = fmaf(xv, wa.z, acc[2]);  acc[3]  = fmaf(xv, wa.w, acc[3]);
        acc[4]  = fmaf(xv, wb.x, acc[4]);  acc[5]  = fmaf(xv, wb.y, acc[5]);
        acc[6]  = fmaf(xv, wb.z, acc[6]);  acc[7]  = fmaf(xv, wb.w, acc[7]);
        acc[8]  = fmaf(xv, wc.x, acc[8]);  acc[9]  = fmaf(xv, wc.y, acc[9]);
        acc[10] = fmaf(xv, wc.z, acc[10]); acc[11] = fmaf(xv, wc.w, acc[11]);
        acc[12] = fmaf(xv, wd.x, acc[12]); acc[13] = fmaf(xv, wd.y, acc[13]);
        acc[14] = fmaf(xv, wd.z, acc[14]); acc[15] = fmaf(xv, wd.w, acc[15]);
    }
#pragma unroll
    for (int off = 32; off > 0; off >>= 1) {
#pragma unroll
        for (int j = 0; j < 16; ++j) acc[j] += __shfl_xor(acc[j], off, 64);
    }

    float h[16];
#pragma unroll
    for (int j = 0; j < 16; ++j) h[j] = gelu_exact(acc[j] + rb1[j]);

    float logits[8];
#pragma unroll
    for (int e = 0; e < 8; ++e) {
        float s = rb2[e];
#pragma unroll
        for (int j = 0; j < 16; ++j) s = fmaf(h[j], rw2[j * 8 + e], s);
        logits[e] = s;
    }
    float m = logits[0];
#pragma unroll
    for (int e = 1; e < 8; ++e) m = fmaxf(m, logits[e]);
    float p[8];
    float sum = 0.f;
#pragma unroll
    for (int e = 0; e < 8; ++e) { p[e] = expf(logits[e] - m); sum += p[e]; }
    float inv = 1.f / sum;
#pragma unroll
    for (int e = 0; e < 8; ++e) p[e] *= inv;

    int i1 = 0; float w1v = p[0];
#pragma unroll
    for (int e = 1; e < 8; ++e) if (p[e] > w1v) { w1v = p[e]; i1 = e; }
    int i2 = -1; float w2v = -1.f;
#pragma unroll
    for (int e = 0; e < 8; ++e) if (e != i1 && p[e] > w2v) { w2v = p[e]; i2 = e; }

    if (lane == 0) {
        tt_idx[t] = i1 | (i2 << 8);
        tt_w[t] = make_float2(w1v, w2v);
        atomicAdd(&ctrl[CTRL_COUNTS + i1], 1);
        atomicAdd(&ctrl[CTRL_COUNTS + i2], 1);
    }
}

__global__ void finalize_kernel(int* __restrict__ ctrl, int* __restrict__ row_token,
                                float* __restrict__ row_w) {
    if (threadIdx.x == 0) {
        int off = 0;
        for (int e = 0; e < NEXP; ++e) {
            ctrl[CTRL_OFFS + e] = off;
            ctrl[CTRL_CURS + e] = off;
            int c = ctrl[CTRL_COUNTS + e];
            off += (c + TILE - 1) & ~(TILE - 1);
        }
        ctrl[CTRL_OFFS + NEXP] = off;
    }
    for (int i = threadIdx.x; i < ROWS_MAX; i += blockDim.x) {
        row_token[i] = 0;
        row_w[i] = 0.f;
    }
}

__global__ void scatter_kernel(const int* __restrict__ tt_idx,
                               const float2* __restrict__ tt_w,
                               int* __restrict__ ctrl, int* __restrict__ row_token,
                               float* __restrict__ row_w) {
    int t = blockIdx.x * blockDim.x + threadIdx.x;
    if (t >= B_TOK) return;
    int packed = tt_idx[t];
    float2 w = tt_w[t];
    int e1 = packed & 0xff, e2 = (packed >> 8) & 0xff;
    int p1 = atomicAdd(&ctrl[CTRL_CURS + e1], 1);
    row_token[p1] = t; row_w[p1] = w.x;
    int p2 = atomicAdd(&ctrl[CTRL_CURS + e2], 1);
    row_token[p2] = t; row_w[p2] = w.y;
}

// ---------------- pre-conversion kernels (bf16 fast path) ----------------

__global__ __launch_bounds__(256)
void conv_x_kernel(const float* __restrict__ x, unsigned short* __restrict__ xh,
                   unsigned short* __restrict__ xl) {
    size_t i = ((size_t)blockIdx.x * 256 + threadIdx.x) * 8;
    float4 v0 = *(const float4*)(x + i);
    float4 v1 = *(const float4*)(x + i + 4);
    s16x8 vh, vl;
    unsigned short h, lo;
    split2(v0.x, h, lo); vh[0] = (short)h; vl[0] = (short)lo;
    split2(v0.y, h, lo); vh[1] = (short)h; vl[1] = (short)lo;
    split2(v0.z, h, lo); vh[2] = (short)h; vl[2] = (short)lo;
    split2(v0.w, h, lo); vh[3] = (short)h; vl[3] = (short)lo;
    split2(v1.x, h, lo); vh[4] = (short)h; vl[4] = (short)lo;
    split2(v1.y, h, lo); vh[5] = (short)h; vl[5] = (short)lo;
    split2(v1.z, h, lo); vh[6] = (short)h; vl[6] = (short)lo;
    split2(v1.w, h, lo); vh[7] = (short)h; vl[7] = (short)lo;
    *(s16x8*)(xh + i) = vh;
    *(s16x8*)(xl + i) = vl;
}

// W [e][K][N] fp32 -> transposed hi/lo planes [e][N][K] (64x64 LDS tile transpose).
__global__ __launch_bounds__(256)
void conv_w_kernel(const float* __restrict__ w, unsigned short* __restrict__ dh,
                   unsigned short* __restrict__ dl, int K, int N) {
    const int e = blockIdx.z, nt = blockIdx.x, kt = blockIdx.y;
    __shared__ float tile[64][65];
    const float* src = w + (size_t)e * K * N;
    const int t = threadIdx.x;
#pragma unroll
    for (int p = 0; p < 4; ++p) {
        int kl = (t >> 4) + p * 16, nl = (t & 15) * 4;
        const float* s = src + (size_t)(kt * 64 + kl) * N + nt * 64 + nl;
        float4 v = *(const float4*)s;
        tile[kl][nl] = v.x; tile[kl][nl + 1] = v.y;
        tile[kl][nl + 2] = v.z; tile[kl][nl + 3] = v.w;
    }
    __syncthreads();
#pragma unroll
    for (int p = 0; p < 4; ++p) {
        int nl = (t >> 4) + p * 16, kl = (t & 15) * 4;
        ushort4 h4, l4;
        split2(tile[kl][nl], h4.x, l4.x);
        split2(tile[kl + 1][nl], h4.y, l4.y);
        split2(tile[kl + 2][nl], h4.z, l4.z);
        split2(tile[kl + 3][nl], h4.w, l4.w);
        size_t off = ((size_t)e * N + nt * 64 + nl) * K + kt * 64 + kl;
        *(ushort4*)(dh + off) = h4;
        *(ushort4*)(dl + off) = l4;
    }
}

// ---------------- MFMA split-bf16 expert GEMMs ----------------
// 128x128 tile, 4 waves (2x2), 4x4 16x16 frags/wave, BK=32.
// LDS rows = 32 bf16 (64B), k-chunk slot s holds global chunk s^((row>>1)&3)
// (swizzle applied on the per-lane GLOBAL address; LDS stays linear).

__global__ __launch_bounds__(256)
void mm1_bf16(const unsigned short* __restrict__ xh, const unsigned short* __restrict__ xl,
              const unsigned short* __restrict__ wh, const unsigned short* __restrict__ wl,
              const float* __restrict__ b1, const int* __restrict__ ctrl,
              const int* __restrict__ row_token,
              unsigned short* __restrict__ hidh, unsigned short* __restrict__ hidl,
              int rbase) {
    const int total = ctrl[CTRL_OFFS + NEXP];
    const int rtile = rbase + blockIdx.y * TILE;
    if (rtile >= total) return;
    int e = 0;
#pragma unroll
    for (int j = 1; j < NEXP; ++j) if (rtile >= ctrl[CTRL_OFFS + j]) e = j;

    __shared__ unsigned short AsH[128 * 32], AsL[128 * 32], BsH[128 * 32], BsL[128 * 32];

    const int tid = threadIdx.x;
    const int l = tid & 63, w = tid >> 6;
    const int l15 = l & 15, l4 = l >> 4;
    const int wr = w >> 1, wc = w & 1;
    const int ntile = blockIdx.x * TILE;

    const int srow = l >> 2, sslot = l & 3;
    const int ar0 = 32 * w + srow, ar1 = ar0 + 16;
    const int kc0 = sslot ^ ((ar0 >> 1) & 3);
    const int kc1 = sslot ^ ((ar1 >> 1) & 3);

    const int tok0 = row_token[rtile + ar0];
    const int tok1 = row_token[rtile + ar1];
    const unsigned short* a0h = xh + (size_t)tok0 * IN_D + kc0 * 8;
    const unsigned short* a1h = xh + (size_t)tok1 * IN_D + kc1 * 8;
    const unsigned short* a0l = xl + (size_t)tok0 * IN_D + kc0 * 8;
    const unsigned short* a1l = xl + (size_t)tok1 * IN_D + kc1 * 8;

    const unsigned short* wbh = wh + ((size_t)e * HID_D + ntile) * (size_t)IN_D;
    const unsigned short* wbl = wl + ((size_t)e * HID_D + ntile) * (size_t)IN_D;
    const unsigned short* b0h = wbh + (size_t)ar0 * IN_D + kc0 * 8;
    const unsigned short* b1h_ = wbh + (size_t)ar1 * IN_D + kc1 * 8;
    const unsigned short* b0l = wbl + (size_t)ar0 * IN_D + kc0 * 8;
    const unsigned short* b1l_ = wbl + (size_t)ar1 * IN_D + kc1 * 8;

    unsigned short* dAH0 = &AsH[(32 * w) * 32];
    unsigned short* dAH1 = &AsH[(32 * w + 16) * 32];
    unsigned short* dAL0 = &AsL[(32 * w) * 32];
    unsigned short* dAL1 = &AsL[(32 * w + 16) * 32];
    unsigned short* dBH0 = &BsH[(32 * w) * 32];
    unsigned short* dBH1 = &BsH[(32 * w + 16) * 32];
    unsigned short* dBL0 = &BsL[(32 * w) * 32];
    unsigned short* dBL1 = &BsL[(32 * w + 16) * 32];

    int aoff[4], boff[4];
#pragma unroll
    for (int mf = 0; mf < 4; ++mf) {
        int r = wr * 64 + mf * 16 + l15;
        aoff[mf] = r * 32 + ((l4 ^ ((r >> 1) & 3)) * 8);
    }
#pragma unroll
    for (int nf = 0; nf < 4; ++nf) {
        int c = wc * 64 + nf * 16 + l15;
        boff[nf] = c * 32 + ((l4 ^ ((c >> 1) & 3)) * 8);
    }

    f32x4 acc[4][4];
#pragma unroll
    for (int i = 0; i < 4; ++i)
#pragma unroll
        for (int j = 0; j < 4; ++j) acc[i][j] = (f32x4){0.f, 0.f, 0.f, 0.f};

    for (int k0 = 0; k0 < IN_D; k0 += 32) {
        __syncthreads();
        gl16(a0h + k0, dAH0); gl16(a1h + k0, dAH1);
        gl16(a0l + k0, dAL0); gl16(a1l + k0, dAL1);
        gl16(b0h + k0, dBH0); gl16(b1h_ + k0, dBH1);
        gl16(b0l + k0, dBL0); gl16(b1l_ + k0, dBL1);
        __syncthreads();

        s16x8 ah[4], al_[4], bh[4], bl_[4];
#pragma unroll
        for (int i = 0; i < 4; ++i) {
            ah[i] = *(const s16x8*)&AsH[aoff[i]];
            al_[i] = *(const s16x8*)&AsL[aoff[i]];
        }
#pragma unroll
        for (int i = 0; i < 4; ++i) {
            bh[i] = *(const s16x8*)&BsH[boff[i]];
            bl_[i] = *(const s16x8*)&BsL[boff[i]];
        }
#pragma unroll
        for (int mf = 0; mf < 4; ++mf)
#pragma unroll
            for (int nf = 0; nf < 4; ++nf) {
                acc[mf][nf] = __builtin_amdgcn_mfma_f32_16x16x32_bf16(ah[mf], bh[nf], acc[mf][nf], 0, 0, 0);
                acc[mf][nf] = __builtin_amdgcn_mfma_f32_16x16x32_bf16(al_[mf], bh[nf], acc[mf][nf], 0, 0, 0);
                acc[mf][nf] = __builtin_amdgcn_mfma_f32_16x16x32_bf16(ah[mf], bl_[nf], acc[mf][nf], 0, 0, 0);
            }
    }

    float bval[4];
#pragma unroll
    for (int nf = 0; nf < 4; ++nf)
        bval[nf] = b1[(size_t)e * HID_D + ntile + wc * 64 + nf * 16 + l15];
    const size_t hbase = (size_t)(rtile - rbase);
#pragma unroll
    for (int mf = 0; mf < 4; ++mf)
#pragma unroll
        for (int r = 0; r < 4; ++r) {
            size_t row = hbase + wr * 64 + mf * 16 + l4 * 4 + r;
            size_t ro = row * HID_D + ntile + wc * 64 + l15;
#pragma unroll
            for (int nf = 0; nf < 4; ++nf) {
                float v = gelu_exact(acc[mf][nf][r] + bval[nf]);
                unsigned short h, lo;
                split2(v, h, lo);
                hidh[ro + nf * 16] = h;
                hidl[ro + nf * 16] = lo;
            }
        }
}

__global__ __launch_bounds__(256)
void mm2_bf16(const unsigned short* __restrict__ hidh, const unsigned short* __restrict__ hidl,
              const unsigned short* __restrict__ wh, const unsigned short* __restrict__ wl,
              const float* __restrict__ b2, const int* __restrict__ ctrl,
              const int* __restrict__ row_token, const float* __restrict__ row_w,
              float* __restrict__ out, int rbase) {
    const int total = ctrl[CTRL_OFFS + NEXP];
    const int rtile = rbase + blockIdx.y * TILE;
    if (rtile >= total) return;
    int e = 0;
#pragma unroll
    for (int j = 1; j < NEXP; ++j) if (rtile >= ctrl[CTRL_OFFS + j]) e = j;

    __shared__ unsigned short AsH[128 * 32], AsL[128 * 32], BsH[128 * 32], BsL[128 * 32];

    const int tid = threadIdx.x;
    const int l = tid & 63, w = tid >> 6;
    const int l15 = l & 15, l4 = l >> 4;
    const int wr = w >> 1, wc = w & 1;
    const int ntile = blockIdx.x * TILE;

    const int srow = l >> 2, sslot = l & 3;
    const int ar0 = 32 * w + srow, ar1 = ar0 + 16;
    const int kc0 = sslot ^ ((ar0 >> 1) & 3);
    const int kc1 = sslot ^ ((ar1 >> 1) & 3);

    const size_t lr0 = (size_t)(rtile - rbase) + ar0;
    const size_t lr1 = lr0 + 16;
    const unsigned short* a0h = hidh + lr0 * HID_D + kc0 * 8;
    const unsigned short* a1h = hidh + lr1 * HID_D + kc1 * 8;
    const unsigned short* a0l = hidl + lr0 * HID_D + kc0 * 8;
    const unsigned short* a1l = hidl + lr1 * HID_D + kc1 * 8;

    const unsigned short* wbh = wh + ((size_t)e * OUT_D + ntile) * (size_t)HID_D;
    const unsigned short* wbl = wl + ((size_t)e * OUT_D + ntile) * (size_t)HID_D;
    const unsigned short* b0h = wbh + (size_t)ar0 * HID_D + kc0 * 8;
    const unsigned short* b1h_ = wbh + (size_t)ar1 * HID_D + kc1 * 8;
    const unsigned short* b0l = wbl + (size_t)ar0 * HID_D + kc0 * 8;
    const unsigned short* b1l_ = wbl + (size_t)ar1 * HID_D + kc1 * 8;

    unsigned short* dAH0 = &AsH[(32 * w) * 32];
    unsigned short* dAH1 = &AsH[(32 * w + 16) * 32];
    unsigned short* dAL0 = &AsL[(32 * w) * 32];
    unsigned short* dAL1 = &AsL[(32 * w + 16) * 32];
    unsigned short* dBH0 = &BsH[(32 * w) * 32];
    unsigned short* dBH1 = &BsH[(32 * w + 16) * 32];
    unsigned short* dBL0 = &BsL[(32 * w) * 32];
    unsigned short* dBL1 = &BsL[(32 * w + 16) * 32];

    int aoff[4], boff[4];
#pragma unroll
    for (int mf = 0; mf < 4; ++mf) {
        int r = wr * 64 + mf * 16 + l15;
        aoff[mf] = r * 32 + ((l4 ^ ((r >> 1) & 3)) * 8);
    }
#pragma unroll
    for (int nf = 0; nf < 4; ++nf) {
        int c = wc * 64 + nf * 16 + l15;
        boff[nf] = c * 32 + ((l4 ^ ((c >> 1) & 3)) * 8);
    }

    f32x4 acc[4][4];
#pragma unroll
    for (int i = 0; i < 4; ++i)
#pragma unroll
        for (int j = 0; j < 4; ++j) acc[i][j] = (f32x4){0.f, 0.f, 0.f, 0.f};

    for (int k0 = 0; k0 < HID_D; k0 += 32) {
        __syncthreads();
        gl16(a0h + k0, dAH0); gl16(a1h + k0, dAH1);
        gl16(a0l + k0, dAL0); gl16(a1l + k0, dAL1);
        gl16(b0h + k0, dBH0); gl16(b1h_ + k0, dBH1);
        gl16(b0l + k0, dBL0); gl16(b1l_ + k0, dBL1);
        __syncthreads();

        s16x8 ah[4], al_[4], bh[4], bl_[4];
#pragma unroll
        for (int i = 0; i < 4; ++i) {
            ah[i] = *(const s16x8*)&AsH[aoff[i]];
            al_[i] = *(const s16x8*)&AsL[aoff[i]];
        }
#pragma unroll
        for (int i = 0; i < 4; ++i) {
            bh[i] = *(const s16x8*)&BsH[boff[i]];
            bl_[i] = *(const s16x8*)&BsL[boff[i]];
        }
#pragma unroll
        for (int mf = 0; mf < 4; ++mf)
#pragma unroll
            for (int nf = 0; nf < 4; ++nf) {
                acc[mf][nf] = __builtin_amdgcn_mfma_f32_16x16x32_bf16(ah[mf], bh[nf], acc[mf][nf], 0, 0, 0);
                acc[mf][nf] = __builtin_amdgcn_mfma_f32_16x16x32_bf16(al_[mf], bh[nf], acc[mf][nf], 0, 0, 0);
                acc[mf][nf] = __builtin_amdgcn_mfma_f32_16x16x32_bf16(ah[mf], bl_[nf], acc[mf][nf], 0, 0, 0);
            }
    }

    float bval[4];
#pragma unroll
    for (int nf = 0; nf < 4; ++nf)
        bval[nf] = b2[(size_t)e * OUT_D + ntile + wc * 64 + nf * 16 + l15];
#pragma unroll
    for (int mf = 0; mf < 4; ++mf)
#pragma unroll
        for (int r = 0; r < 4; ++r) {
            int rg = rtile + wr * 64 + mf * 16 + l4 * 4 + r;
            float wv = row_w[rg];
            if (wv != 0.f) {
                int tok = row_token[rg];
                float* op = out + (size_t)tok * OUT_D + ntile + wc * 64 + l15;
#pragma unroll
                for (int nf = 0; nf < 4; ++nf)
                    atomicAdd(op + nf * 16, wv * (acc[mf][nf][r] + bval[nf]));
            }
        }
}

// ---------------- fp32 fallback GEMMs (round-0, audited) ----------------

__global__ __launch_bounds__(256)
void expert_gemm1(const float* __restrict__ x, const float* __restrict__ w1,
                  const float* __restrict__ b1, const int* __restrict__ ctrl,
                  const int* __restrict__ row_token, float* __restrict__ hidden,
                  int rbase) {
    const int total = ctrl[CTRL_OFFS + NEXP];
    const int rtile = rbase + blockIdx.y * TILE;
    if (rtile >= total) return;
    int e = 0;
#pragma unroll
    for (int j = 1; j < NEXP; ++j) if (rtile >= ctrl[CTRL_OFFS + j]) e = j;

    const float* __restrict__ W = w1 + (size_t)e * IN_D * HID_D;
    const float* __restrict__ bias = b1 + (size_t)e * HID_D;
    const int ntile = blockIdx.x * TILE;

    __shared__ float As[BK][TILE];
    __shared__ float Bs[BK][TILE];

    const int tid = threadIdx.x;
    const int tx = tid & 15, ty = tid >> 4;
    const int tm0 = ty * 8, tn0 = tx * 8;

    const int arow = tid >> 1;
    const int akk = (tid & 1) * 8;
    const int tok = row_token[rtile + arow];
    const float* __restrict__ xrow = x + (size_t)tok * IN_D + akk;

    const int bkk = tid >> 4;
    const int bn = (tid & 15) * 8;
    const float* __restrict__ wrow = W + (size_t)bkk * HID_D + ntile + bn;

    float acc[8][8];
#pragma unroll
    for (int i = 0; i < 8; ++i)
#pragma unroll
        for (int j = 0; j < 8; ++j) acc[i][j] = 0.f;

    for (int k0 = 0; k0 < IN_D; k0 += BK) {
        float4 a0 = *(const float4*)(xrow + k0);
        float4 a1 = *(const float4*)(xrow + k0 + 4);
        float4 bv0 = *(const float4*)(wrow + (size_t)k0 * HID_D);
        float4 bv1 = *(const float4*)(wrow + (size_t)k0 * HID_D + 4);
        __syncthreads();
        As[akk + 0][arow] = a0.x; As[akk + 1][arow] = a0.y;
        As[akk + 2][arow] = a0.z; As[akk + 3][arow] = a0.w;
        As[akk + 4][arow] = a1.x; As[akk + 5][arow] = a1.y;
        As[akk + 6][arow] = a1.z; As[akk + 7][arow] = a1.w;
        *(float4*)&Bs[bkk][bn] = bv0;
        *(float4*)&Bs[bkk][bn + 4] = bv1;
        __syncthreads();
#pragma unroll
        for (int k = 0; k < BK; ++k) {
            float a_[8], b_[8];
            *(float4*)&a_[0] = *(const float4*)&As[k][tm0];
            *(float4*)&a_[4] = *(const float4*)&As[k][tm0 + 4];
            *(float4*)&b_[0] = *(const float4*)&Bs[k][tn0];
            *(float4*)&b_[4] = *(const float4*)&Bs[k][tn0 + 4];
#pragma unroll
            for (int i = 0; i < 8; ++i)
#pragma unroll
                for (int j = 0; j < 8; ++j) acc[i][j] = fmaf(a_[i], b_[j], acc[i][j]);
        }
    }

    float bb[8];
#pragma unroll
    for (int j = 0; j < 8; ++j) bb[j] = bias[ntile + tn0 + j];
#pragma unroll
    for (int i = 0; i < 8; ++i) {
        const int grow = rtile + tm0 + i;
        float* hp = hidden + (size_t)(grow - rbase) * HID_D + ntile + tn0;
        float o[8];
#pragma unroll
        for (int j = 0; j < 8; ++j) o[j] = gelu_exact(acc[i][j] + bb[j]);
        *(float4*)hp = make_float4(o[0], o[1], o[2], o[3]);
        *(float4*)(hp + 4) = make_float4(o[4], o[5], o[6], o[7]);
    }
}

__global__ __launch_bounds__(256)
void expert_gemm2(const float* __restrict__ hidden, const float* __restrict__ w2,
                  const float* __restrict__ b2, const int* __restrict__ ctrl,
                  const int* __restrict__ row_token, const float* __restrict__ row_w,
                  float* __restrict__ out, int rbase) {
    const int total = ctrl[CTRL_OFFS + NEXP];
    const int rtile = rbase + blockIdx.y * TILE;
    if (rtile >= total) return;
    int e = 0;
#pragma unroll
    for (int j = 1; j < NEXP; ++j) if (rtile >= ctrl[CTRL_OFFS + j]) e = j;

    const float* __restrict__ W = w2 + (size_t)e * HID_D * OUT_D;
    const float* __restrict__ bias = b2 + (size_t)e * OUT_D;
    const int ntile = blockIdx.x * TILE;

    __shared__ float As[BK][TILE];
    __shared__ float Bs[BK][TILE];

    const int tid = threadIdx.x;
    const int tx = tid & 15, ty = tid >> 4;
    const int tm0 = ty * 8, tn0 = tx * 8;

    const int arow = tid >> 1;
    const int akk = (tid & 1) * 8;
    const float* __restrict__ hrow =
        hidden + (size_t)(rtile - rbase + arow) * HID_D + akk;

    const int bkk = tid >> 4;
    const int bn = (tid & 15) * 8;
    const float* __restrict__ wrow = W + (size_t)bkk * OUT_D + ntile + bn;

    float acc[8][8];
#pragma unroll
    for (int i = 0; i < 8; ++i)
#pragma unroll
        for (int j = 0; j < 8; ++j) acc[i][j] = 0.f;

    for (int k0 = 0; k0 < HID_D; k0 += BK) {
        float4 a0 = *(const float4*)(hrow + k0);
        float4 a1 = *(const float4*)(hrow + k0 + 4);
        float4 bv0 = *(const float4*)(wrow + (size_t)k0 * OUT_D);
        float4 bv1 = *(const float4*)(wrow + (size_t)k0 * OUT_D + 4);
        __syncthreads();
        As[akk + 0][arow] = a0.x; As[akk + 1][arow] = a0.y;
        As[akk + 2][arow] = a0.z; As[akk + 3][arow] = a0.w;
        As[akk + 4][arow] = a1.x; As[akk + 5][arow] = a1.y;
        As[akk + 6][arow] = a1.z; As[akk + 7][arow] = a1.w;
        *(float4*)&Bs[bkk][bn] = bv0;
        *(float4*)&Bs[bkk][bn + 4] = bv1;
        __syncthreads();
#pragma unroll
        for (int k = 0; k < BK; ++k) {
            float a_[8], b_[8];
            *(float4*)&a_[0] = *(const float4*)&As[k][tm0];
            *(float4*)&a_[4] = *(const float4*)&As[k][tm0 + 4];
            *(float4*)&b_[0] = *(const float4*)&Bs[k][tn0];
            *(float4*)&b_[4] = *(const float4*)&Bs[k][tn0 + 4];
#pragma unroll
            for (int i = 0; i < 8; ++i)
#pragma unroll
                for (int j = 0; j < 8; ++j) acc[i][j] = fmaf(a_[i], b_[j], acc[i][j]);
        }
    }

    float bb[8];
#pragma unroll
    for (int j = 0; j < 8; ++j) bb[j] = bias[ntile + tn0 + j];
#pragma unroll
    for (int i = 0; i < 8; ++i) {
        const int grow = rtile + tm0 + i;
        const float wv = row_w[grow];
        if (wv != 0.f) {
            const int tok = row_token[grow];
            float* op = out + (size_t)tok * OUT_D + ntile + tn0;
#pragma unroll
            for (int j = 0; j < 8; ++j) atomicAdd(op + j, wv * (acc[i][j] + bb[j]));
        }
    }
}

// ---------------- host ----------------

extern "C" void kernel_launch(void* const* d_in, const int* in_sizes, int n_in,
                              void* d_out, int out_size, void* d_ws, size_t ws_size,
                              hipStream_t stream) {
    const float* x   = (const float*)d_in[0];
    const float* sig = (const float*)d_in[1];
    const float* tc  = (const float*)d_in[2];
    const float* rs  = (const float*)d_in[3];
    const float* rw1 = (const float*)d_in[4];
    const float* rb1 = (const float*)d_in[5];
    const float* rw2 = (const float*)d_in[6];
    const float* rb2 = (const float*)d_in[7];
    const float* ew1 = (const float*)d_in[8];
    const float* eb1 = (const float*)d_in[9];
    const float* ew2 = (const float*)d_in[10];
    const float* eb2 = (const float*)d_in[11];
    float* out = (float*)d_out;

    char* ws = (char*)d_ws;
    int* ctrl = (int*)ws;                                         // 4 KB
    int* tt_idx = (int*)(ws + 4096);                              // 64 KB
    float2* tt_w = (float2*)(ws + 69632);                         // 128 KB
    int* row_token = (int*)(ws + 200704);                         // 132 KB
    float* row_w = (float*)(ws + 335872);                         // 132 KB
    const size_t MAPS_END = 471040;

    const size_t XB = (size_t)B_TOK * IN_D * 2;                   // 32 MB / plane
    const size_t WB = (size_t)NEXP * IN_D * HID_D * 2;            // 64 MB / plane
    unsigned short* xh  = (unsigned short*)(ws + MAPS_END);
    unsigned short* xl  = (unsigned short*)(ws + MAPS_END + XB);
    unsigned short* w1h = (unsigned short*)(ws + MAPS_END + 2 * XB);
    unsigned short* w1l = (unsigned short*)(ws + MAPS_END + 2 * XB + WB);
    unsigned short* w2h = (unsigned short*)(ws + MAPS_END + 2 * XB + 2 * WB);
    unsigned short* w2l = (unsigned short*)(ws + MAPS_END + 2 * XB + 3 * WB);
    const size_t FIXED_END = MAPS_END + 2 * XB + 4 * WB;          // ~320.5 MB

    // ws-size gates (R6 hardening): never launch a kernel that writes beyond ws.
    const bool maps_ok  = ws_size >= MAPS_END;                              // routing tables fit
    const bool fp32_ok  = ws_size >= MAPS_END + (size_t)TILE * HID_D * 4;   // >=128 fp32 hidden rows
    const bool bf16_path = ws_size >= FIXED_END + (size_t)TILE * HID_D * 4; // planes + >=128 bf16 hi/lo rows

    // Output must always be defined: zero it unconditionally (atomic combine adds on top).
    hipLaunchKernelGGL(zero_out_kernel, dim3(2048), dim3(256), 0, stream,
                       (float4*)out, B_TOK * OUT_D / 4);
    if (!maps_ok) return;  // cannot do anything safely; deterministic zero output

    hipLaunchKernelGGL(zero_ctrl_kernel, dim3(1), dim3(64), 0, stream, ctrl);
    hipLaunchKernelGGL(router_kernel, dim3(B_TOK / 4), dim3(256), 0, stream,
                       x, sig, tc, rs, rw1, rb1, rw2, rb2, ctrl, tt_idx, tt_w);
    hipLaunchKernelGGL(finalize_kernel, dim3(1), dim3(256), 0, stream,
                       ctrl, row_token, row_w);
    hipLaunchKernelGGL(scatter_kernel, dim3(B_TOK / 256), dim3(256), 0, stream,
                       tt_idx, tt_w, ctrl, row_token, row_w);

    if (bf16_path) {
        size_t avail = ws_size - FIXED_END;
        long long q = (long long)(avail / ((size_t)HID_D * 4));
        int qrows = (int)(q > ROWS_MAX ? ROWS_MAX : q);
        qrows &= ~(TILE - 1);   // bf16_path guarantees qrows >= TILE
        unsigned short* hidh = (unsigned short*)(ws + FIXED_END);
        unsigned short* hidl = hidh + (size_t)qrows * HID_D;
        const int ngroups = (ROWS_MAX + qrows - 1) / qrows;

        hipLaunchKernelGGL(conv_x_kernel, dim3(B_TOK * IN_D / 8 / 256), dim3(256),
                           0, stream, x, xh, xl);
        hipLaunchKernelGGL(conv_w_kernel, dim3(HID_D / 64, IN_D / 64, NEXP), dim3(256),
                           0, stream, ew1, w1h, w1l, IN_D, HID_D);
        hipLaunchKernelGGL(conv_w_kernel, dim3(OUT_D / 64, HID_D / 64, NEXP), dim3(256),
                           0, stream, ew2, w2h, w2l, HID_D, OUT_D);

        for (int g = 0; g < ngroups; ++g) {
            const int rbase = g * qrows;
            hipLaunchKernelGGL(mm1_bf16, dim3(HID_D / TILE, qrows / TILE), dim3(256),
                               0, stream, xh, xl, w1h, w1l, eb1, ctrl, row_token,
                               hidh, hidl, rbase);
            hipLaunchKernelGGL(mm2_bf16, dim3(OUT_D / TILE, qrows / TILE), dim3(256),
                               0, stream, hidh, hidl, w2h, w2l, eb2, ctrl, row_token,
                               row_w, out, rbase);
        }
    } else if (fp32_ok) {
        float* hidden = (float*)(ws + MAPS_END);
        size_t avail = ws_size - MAPS_END;
        long long q = (long long)(avail / ((size_t)HID_D * sizeof(float)));
        int qrows = (int)(q > ROWS_MAX ? ROWS_MAX : q);
        qrows &= ~(TILE - 1);   // fp32_ok guarantees qrows >= TILE
        const int ngroups = (ROWS_MAX + qrows - 1) / qrows;
        for (int g = 0; g < ngroups; ++g) {
            const int rbase = g * qrows;
            hipLaunchKernelGGL(expert_gemm1, dim3(HID_D / TILE, qrows / TILE), dim3(256),
                               0, stream, x, ew1, eb1, ctrl, row_token, hidden, rbase);
            hipLaunchKernelGGL(expert_gemm2, dim3(OUT_D / TILE, qrows / TILE), dim3(256),
                               0, stream, hidden, ew2, eb2, ctrl, row_token, row_w, out, rbase);
        }
    }
    // else: routing ran but no GEMM workspace — output stays zero (clean failure signal).
}

// Round 9
// 1857.767 us; speedup vs baseline: 1.8497x; 1.8497x over previous
//
#include <hip/hip_runtime.h>
#include <math.h>

// ---------------------------------------------------------------------------
// PhysicalMoE — routed (top-2) MoE. R7 (resubmitted R8 — never benched):
//  * single-fp16 planes (was split-bf16 3-product): 3x fewer MFMA, 2x less
//    traffic; predicted absmax ~5e-3 (fp32-accumulate fp16 GEMM).
//  * double-buffered LDS staging (prefetch k+1 during k), 1 barrier/K-step.
//  * XCD-chunked 1D block swizzle: same-row-panel tiles share one XCD's L2.
// Routing scaffolding + fp32 fallback unchanged (HW-validated R7 bench).
// ---------------------------------------------------------------------------

#define B_TOK 16384
#define IN_D 1024
#define HID_D 4096
#define OUT_D 1024
#define NEXP 8
#define SIG_D 32
#define RIN 1059

#define TILE 128
#define BK 16  // fp32 fallback k-step
#define ROWS_MAX 33792

#define CTRL_COUNTS 0
#define CTRL_CURS 8
#define CTRL_OFFS 16

typedef float f32x4 __attribute__((ext_vector_type(4)));
typedef _Float16 f16x8 __attribute__((ext_vector_type(8)));
typedef short s16x8 __attribute__((ext_vector_type(8)));

__device__ __forceinline__ float gelu_exact(float v) {
    return 0.5f * v * (1.0f + erff(v * 0.70710678118654752440f));
}

__device__ __forceinline__ unsigned short f2h(float f) {
    _Float16 h = (_Float16)f;  // RTNE
    unsigned short u;
    __builtin_memcpy(&u, &h, 2);
    return u;
}

// global -> LDS direct (16B/lane). lds base wave-uniform; HW scatters lane i at
// base + i*16. Global src per-lane (carries the XOR swizzle). [HW-validated R7]
__device__ __forceinline__ void gl16(const unsigned short* g, unsigned short* lds) {
    __builtin_amdgcn_global_load_lds(
        (const __attribute__((address_space(1))) void*)g,
        (__attribute__((address_space(3))) void*)lds, 16, 0, 0);
}

// ---------------- control / routing (HW-validated, unchanged) ----------------

__global__ void zero_ctrl_kernel(int* ctrl) {
    if (threadIdx.x < 32) ctrl[threadIdx.x] = 0;
}

__global__ void zero_out_kernel(float4* out, int n4) {
    int i = blockIdx.x * blockDim.x + threadIdx.x;
    int stride = gridDim.x * blockDim.x;
    for (; i < n4; i += stride) out[i] = make_float4(0.f, 0.f, 0.f, 0.f);
}

__global__ __launch_bounds__(256)
void router_kernel(const float* __restrict__ x, const float* __restrict__ sig,
                   const float* __restrict__ tc, const float* __restrict__ rs,
                   const float* __restrict__ rw1, const float* __restrict__ rb1,
                   const float* __restrict__ rw2, const float* __restrict__ rb2,
                   int* __restrict__ ctrl, int* __restrict__ tt_idx,
                   float2* __restrict__ tt_w) {
    const int wave = threadIdx.x >> 6;
    const int lane = threadIdx.x & 63;
    const int t = blockIdx.x * 4 + wave;

    float acc[16];
#pragma unroll
    for (int j = 0; j < 16; ++j) acc[j] = 0.f;

    for (int i = lane; i < RIN; i += 64) {
        float xv;
        if (i < IN_D) xv = x[(size_t)t * IN_D + i];
        else if (i < IN_D + SIG_D) xv = sig[(size_t)t * SIG_D + (i - IN_D)];
        else if (i == IN_D + SIG_D) xv = tc[t];
        else xv = rs[(size_t)t * 2 + (i - (IN_D + SIG_D + 1))];
        const float4* wr = (const float4*)(rw1 + (size_t)i * 16);
        float4 wa = wr[0], wb = wr[1], wc = wr[2], wd = wr[3];
        acc[0]  = fmaf(xv, wa.x, acc[0]);  acc[1]  = fmaf(xv, wa.y, acc[1]);
        acc[2]  = fmaf(xv, wa.z, acc[2]);  acc[3]  = fmaf(xv, wa.w, acc[3]);
        acc[4]  = fmaf(xv, wb.x, acc[4]);  acc[5]  = fmaf(xv, wb.y, acc[5]);
        acc[6]  = fmaf(xv, wb.z, acc[6]);  acc[7]  = fmaf(xv, wb.w, acc[7]);
        acc[8]  = fmaf(xv, wc.x, acc[8]);  acc[9]  = fmaf(xv, wc.y, acc[9]);
        acc[10] = fmaf(xv, wc.z, acc[10]); acc[11] = fmaf(xv, wc.w, acc[11]);
        acc[12] = fmaf(xv, wd.x, acc[12]); acc[13] = fmaf(xv, wd.y, acc[13]);
        acc[14] = fmaf(xv, wd.z, acc[14]); acc[15] = fmaf(xv, wd.w, acc[15]);
    }
#pragma unroll
    for (int off = 32; off > 0; off >>= 1) {
#pragma unroll
        for (int j = 0; j < 16; ++j) acc[j] += __shfl_xor(acc[j], off, 64);
    }

    float h[16];
#pragma unroll
    for (int j = 0; j < 16; ++j) h[j] = gelu_exact(acc[j] + rb1[j]);

    float logits[8];
#pragma unroll
    for (int e = 0; e < 8; ++e) {
        float s = rb2[e];
#pragma unroll
        for (int j = 0; j < 16; ++j) s = fmaf(h[j], rw2[j * 8 + e], s);
        logits[e] = s;
    }
    float m = logits[0];
#pragma unroll
    for (int e = 1; e < 8; ++e) m = fmaxf(m, logits[e]);
    float p[8];
    float sum = 0.f;
#pragma unroll
    for (int e = 0; e < 8; ++e) { p[e] = expf(logits[e] - m); sum += p[e]; }
    float inv = 1.f / sum;
#pragma unroll
    for (int e = 0; e < 8; ++e) p[e] *= inv;

    int i1 = 0; float w1v = p[0];
#pragma unroll
    for (int e = 1; e < 8; ++e) if (p[e] > w1v) { w1v = p[e]; i1 = e; }
    int i2 = -1; float w2v = -1.f;
#pragma unroll
    for (int e = 0; e < 8; ++e) if (e != i1 && p[e] > w2v) { w2v = p[e]; i2 = e; }

    if (lane == 0) {
        tt_idx[t] = i1 | (i2 << 8);
        tt_w[t] = make_float2(w1v, w2v);
        atomicAdd(&ctrl[CTRL_COUNTS + i1], 1);
        atomicAdd(&ctrl[CTRL_COUNTS + i2], 1);
    }
}

__global__ void finalize_kernel(int* __restrict__ ctrl, int* __restrict__ row_token,
                                float* __restrict__ row_w) {
    if (threadIdx.x == 0) {
        int off = 0;
        for (int e = 0; e < NEXP; ++e) {
            ctrl[CTRL_OFFS + e] = off;
            ctrl[CTRL_CURS + e] = off;
            int c = ctrl[CTRL_COUNTS + e];
            off += (c + TILE - 1) & ~(TILE - 1);
        }
        ctrl[CTRL_OFFS + NEXP] = off;
    }
    for (int i = threadIdx.x; i < ROWS_MAX; i += blockDim.x) {
        row_token[i] = 0;
        row_w[i] = 0.f;
    }
}

__global__ void scatter_kernel(const int* __restrict__ tt_idx,
                               const float2* __restrict__ tt_w,
                               int* __restrict__ ctrl, int* __restrict__ row_token,
                               float* __restrict__ row_w) {
    int t = blockIdx.x * blockDim.x + threadIdx.x;
    if (t >= B_TOK) return;
    int packed = tt_idx[t];
    float2 w = tt_w[t];
    int e1 = packed & 0xff, e2 = (packed >> 8) & 0xff;
    int p1 = atomicAdd(&ctrl[CTRL_CURS + e1], 1);
    row_token[p1] = t; row_w[p1] = w.x;
    int p2 = atomicAdd(&ctrl[CTRL_CURS + e2], 1);
    row_token[p2] = t; row_w[p2] = w.y;
}

// ---------------- fp16 pre-conversion ----------------

// x [B][IN] fp32 -> xf fp16 (same layout), 8 elems/thread.
__global__ __launch_bounds__(256)
void conv_x_f16(const float* __restrict__ x, unsigned short* __restrict__ xf) {
    size_t i = ((size_t)blockIdx.x * 256 + threadIdx.x) * 8;
    float4 v0 = *(const float4*)(x + i);
    float4 v1 = *(const float4*)(x + i + 4);
    s16x8 vh;
    vh[0] = (short)f2h(v0.x); vh[1] = (short)f2h(v0.y);
    vh[2] = (short)f2h(v0.z); vh[3] = (short)f2h(v0.w);
    vh[4] = (short)f2h(v1.x); vh[5] = (short)f2h(v1.y);
    vh[6] = (short)f2h(v1.z); vh[7] = (short)f2h(v1.w);
    *(s16x8*)(xf + i) = vh;
}

// W [e][K][N] fp32 -> transposed fp16 plane [e][N][K] (64x64 LDS transpose).
__global__ __launch_bounds__(256)
void conv_w_f16(const float* __restrict__ w, unsigned short* __restrict__ dst,
                int K, int N) {
    const int e = blockIdx.z, nt = blockIdx.x, kt = blockIdx.y;
    __shared__ float tile[64][65];
    const float* src = w + (size_t)e * K * N;
    const int t = threadIdx.x;
#pragma unroll
    for (int p = 0; p < 4; ++p) {
        int kl = (t >> 4) + p * 16, nl = (t & 15) * 4;
        const float* s = src + (size_t)(kt * 64 + kl) * N + nt * 64 + nl;
        float4 v = *(const float4*)s;
        tile[kl][nl] = v.x; tile[kl][nl + 1] = v.y;
        tile[kl][nl + 2] = v.z; tile[kl][nl + 3] = v.w;
    }
    __syncthreads();
#pragma unroll
    for (int p = 0; p < 4; ++p) {
        int nl = (t >> 4) + p * 16, kl = (t & 15) * 4;
        ushort4 h4;
        h4.x = f2h(tile[kl][nl]);
        h4.y = f2h(tile[kl + 1][nl]);
        h4.z = f2h(tile[kl + 2][nl]);
        h4.w = f2h(tile[kl + 3][nl]);
        size_t off = ((size_t)e * N + nt * 64 + nl) * K + kt * 64 + kl;
        *(ushort4*)(dst + off) = h4;
    }
}

// ---------------- fp16 MFMA expert GEMMs ----------------
// 128x128 tile, 4 waves (2x2), 4x4 16x16x32 f16 frags/wave, BK=32.
// LDS double-buffered (8 KB A + 8 KB B per buffer). Staging geometry + XOR
// swizzle identical to the HW-validated R7 kernel (lo-planes dropped).
// Grid flattened 1D with XCD-chunked swizzle: all N-tiles of one row-panel
// land on one XCD (A-panel fetched ~once per XCD L2).

__global__ __launch_bounds__(256)
void mm1_f16(const unsigned short* __restrict__ xf, const unsigned short* __restrict__ wf,
             const float* __restrict__ bia, const int* __restrict__ ctrl,
             const int* __restrict__ row_token, unsigned short* __restrict__ hid,
             int rbase) {
    const int total = ctrl[CTRL_OFFS + NEXP];
    // XCD-chunked bijective swizzle (gridDim.x = 32*ny, divisible by 8)
    const int bper = (int)gridDim.x >> 3;
    const int lin = ((int)blockIdx.x & 7) * bper + ((int)blockIdx.x >> 3);
    const int ty = lin >> 5, tx = lin & 31;  // 32 N-tiles
    const int rtile = rbase + ty * TILE;
    if (rtile >= total) return;
    int e = 0;
#pragma unroll
    for (int j = 1; j < NEXP; ++j) if (rtile >= ctrl[CTRL_OFFS + j]) e = j;
    const int ntile = tx * TILE;

    __shared__ unsigned short As[2 * 128 * 32], Bs[2 * 128 * 32];

    const int tid = threadIdx.x;
    const int l = tid & 63, w = tid >> 6;
    const int l15 = l & 15, l4 = l >> 4;
    const int wr = w >> 1, wc = w & 1;

    // staging: wave w owns rows [32w,32w+32); lane -> (row 32w+(l>>2), slot l&3)
    const int srow = l >> 2, sslot = l & 3;
    const int ar0 = 32 * w + srow, ar1 = ar0 + 16;
    const int kc0 = sslot ^ ((ar0 >> 1) & 3);
    const int kc1 = sslot ^ ((ar1 >> 1) & 3);

    const int tok0 = row_token[rtile + ar0];
    const int tok1 = row_token[rtile + ar1];
    const unsigned short* a0 = xf + (size_t)tok0 * IN_D + kc0 * 8;
    const unsigned short* a1 = xf + (size_t)tok1 * IN_D + kc1 * 8;
    const unsigned short* wb = wf + ((size_t)e * HID_D + ntile) * (size_t)IN_D;
    const unsigned short* b0 = wb + (size_t)ar0 * IN_D + kc0 * 8;
    const unsigned short* b1p = wb + (size_t)ar1 * IN_D + kc1 * 8;

    const int d0 = (32 * w) * 32, d1 = d0 + 16 * 32;  // wave-uniform LDS dests

    int aoff[4], boff[4];
#pragma unroll
    for (int mf = 0; mf < 4; ++mf) {
        int r = wr * 64 + mf * 16 + l15;
        aoff[mf] = r * 32 + ((l4 ^ ((r >> 1) & 3)) * 8);
    }
#pragma unroll
    for (int nf = 0; nf < 4; ++nf) {
        int c = wc * 64 + nf * 16 + l15;
        boff[nf] = c * 32 + ((l4 ^ ((c >> 1) & 3)) * 8);
    }

    f32x4 acc[4][4];
#pragma unroll
    for (int i = 0; i < 4; ++i)
#pragma unroll
        for (int j = 0; j < 4; ++j) acc[i][j] = (f32x4){0.f, 0.f, 0.f, 0.f};

    // prologue: stage k=0 into buffer 0
    gl16(a0, &As[d0]); gl16(a1, &As[d1]);
    gl16(b0, &Bs[d0]); gl16(b1p, &Bs[d1]);
    __syncthreads();
    int cur = 0;
    for (int k0 = 0; k0 < IN_D; k0 += 32) {
        const int nxt = k0 + 32;
        if (nxt < IN_D) {  // prefetch next K-step into the other buffer
            const int bo = (cur ^ 1) * 4096;
            gl16(a0 + nxt, &As[bo + d0]); gl16(a1 + nxt, &As[bo + d1]);
            gl16(b0 + nxt, &Bs[bo + d0]); gl16(b1p + nxt, &Bs[bo + d1]);
        }
        const int ro = cur * 4096;
        f16x8 af[4], bf_[4];
#pragma unroll
        for (int i = 0; i < 4; ++i) af[i] = *(const f16x8*)&As[ro + aoff[i]];
#pragma unroll
        for (int i = 0; i < 4; ++i) bf_[i] = *(const f16x8*)&Bs[ro + boff[i]];
#pragma unroll
        for (int mf = 0; mf < 4; ++mf)
#pragma unroll
            for (int nf = 0; nf < 4; ++nf)
                acc[mf][nf] = __builtin_amdgcn_mfma_f32_16x16x32_f16(af[mf], bf_[nf], acc[mf][nf], 0, 0, 0);
        __syncthreads();  // drains this wave's prefetch (vmcnt0) + read fences
        cur ^= 1;
    }

    float bval[4];
#pragma unroll
    for (int nf = 0; nf < 4; ++nf)
        bval[nf] = bia[(size_t)e * HID_D + ntile + wc * 64 + nf * 16 + l15];
    const size_t hbase = (size_t)(rtile - rbase);
#pragma unroll
    for (int mf = 0; mf < 4; ++mf)
#pragma unroll
        for (int r = 0; r < 4; ++r) {
            size_t row = hbase + wr * 64 + mf * 16 + l4 * 4 + r;
            size_t ro = row * HID_D + ntile + wc * 64 + l15;
#pragma unroll
            for (int nf = 0; nf < 4; ++nf)
                hid[ro + nf * 16] = f2h(gelu_exact(acc[mf][nf][r] + bval[nf]));
        }
}

__global__ __launch_bounds__(256)
void mm2_f16(const unsigned short* __restrict__ hid, const unsigned short* __restrict__ wf,
             const float* __restrict__ bia, const int* __restrict__ ctrl,
             const int* __restrict__ row_token, const float* __restrict__ row_w,
             float* __restrict__ out, int rbase) {
    const int total = ctrl[CTRL_OFFS + NEXP];
    const int bper = (int)gridDim.x >> 3;
    const int lin = ((int)blockIdx.x & 7) * bper + ((int)blockIdx.x >> 3);
    const int ty = lin >> 3, tx = lin & 7;  // 8 N-tiles
    const int rtile = rbase + ty * TILE;
    if (rtile >= total) return;
    int e = 0;
#pragma unroll
    for (int j = 1; j < NEXP; ++j) if (rtile >= ctrl[CTRL_OFFS + j]) e = j;
    const int ntile = tx * TILE;

    __shared__ unsigned short As[2 * 128 * 32], Bs[2 * 128 * 32];

    const int tid = threadIdx.x;
    const int l = tid & 63, w = tid >> 6;
    const int l15 = l & 15, l4 = l >> 4;
    const int wr = w >> 1, wc = w & 1;

    const int srow = l >> 2, sslot = l & 3;
    const int ar0 = 32 * w + srow, ar1 = ar0 + 16;
    const int kc0 = sslot ^ ((ar0 >> 1) & 3);
    const int kc1 = sslot ^ ((ar1 >> 1) & 3);

    const size_t lr0 = (size_t)(rtile - rbase) + ar0;
    const unsigned short* a0 = hid + lr0 * HID_D + kc0 * 8;
    const unsigned short* a1 = hid + (lr0 + 16) * HID_D + kc1 * 8;
    const unsigned short* wb = wf + ((size_t)e * OUT_D + ntile) * (size_t)HID_D;
    const unsigned short* b0 = wb + (size_t)ar0 * HID_D + kc0 * 8;
    const unsigned short* b1p = wb + (size_t)ar1 * HID_D + kc1 * 8;

    const int d0 = (32 * w) * 32, d1 = d0 + 16 * 32;

    int aoff[4], boff[4];
#pragma unroll
    for (int mf = 0; mf < 4; ++mf) {
        int r = wr * 64 + mf * 16 + l15;
        aoff[mf] = r * 32 + ((l4 ^ ((r >> 1) & 3)) * 8);
    }
#pragma unroll
    for (int nf = 0; nf < 4; ++nf) {
        int c = wc * 64 + nf * 16 + l15;
        boff[nf] = c * 32 + ((l4 ^ ((c >> 1) & 3)) * 8);
    }

    f32x4 acc[4][4];
#pragma unroll
    for (int i = 0; i < 4; ++i)
#pragma unroll
        for (int j = 0; j < 4; ++j) acc[i][j] = (f32x4){0.f, 0.f, 0.f, 0.f};

    gl16(a0, &As[d0]); gl16(a1, &As[d1]);
    gl16(b0, &Bs[d0]); gl16(b1p, &Bs[d1]);
    __syncthreads();
    int cur = 0;
    for (int k0 = 0; k0 < HID_D; k0 += 32) {
        const int nxt = k0 + 32;
        if (nxt < HID_D) {
            const int bo = (cur ^ 1) * 4096;
            gl16(a0 + nxt, &As[bo + d0]); gl16(a1 + nxt, &As[bo + d1]);
            gl16(b0 + nxt, &Bs[bo + d0]); gl16(b1p + nxt, &Bs[bo + d1]);
        }
        const int ro = cur * 4096;
        f16x8 af[4], bf_[4];
#pragma unroll
        for (int i = 0; i < 4; ++i) af[i] = *(const f16x8*)&As[ro + aoff[i]];
#pragma unroll
        for (int i = 0; i < 4; ++i) bf_[i] = *(const f16x8*)&Bs[ro + boff[i]];
#pragma unroll
        for (int mf = 0; mf < 4; ++mf)
#pragma unroll
            for (int nf = 0; nf < 4; ++nf)
                acc[mf][nf] = __builtin_amdgcn_mfma_f32_16x16x32_f16(af[mf], bf_[nf], acc[mf][nf], 0, 0, 0);
        __syncthreads();
        cur ^= 1;
    }

    float bval[4];
#pragma unroll
    for (int nf = 0; nf < 4; ++nf)
        bval[nf] = bia[(size_t)e * OUT_D + ntile + wc * 64 + nf * 16 + l15];
#pragma unroll
    for (int mf = 0; mf < 4; ++mf)
#pragma unroll
        for (int r = 0; r < 4; ++r) {
            int rg = rtile + wr * 64 + mf * 16 + l4 * 4 + r;
            float wv = row_w[rg];
            if (wv != 0.f) {
                int tok = row_token[rg];
                float* op = out + (size_t)tok * OUT_D + ntile + wc * 64 + l15;
#pragma unroll
                for (int nf = 0; nf < 4; ++nf)
                    atomicAdd(op + nf * 16, wv * (acc[mf][nf][r] + bval[nf]));
            }
        }
}

// ---------------- fp32 fallback GEMMs (unchanged, gated) ----------------

__global__ __launch_bounds__(256)
void expert_gemm1(const float* __restrict__ x, const float* __restrict__ w1,
                  const float* __restrict__ b1, const int* __restrict__ ctrl,
                  const int* __restrict__ row_token, float* __restrict__ hidden,
                  int rbase) {
    const int total = ctrl[CTRL_OFFS + NEXP];
    const int rtile = rbase + blockIdx.y * TILE;
    if (rtile >= total) return;
    int e = 0;
#pragma unroll
    for (int j = 1; j < NEXP; ++j) if (rtile >= ctrl[CTRL_OFFS + j]) e = j;

    const float* __restrict__ W = w1 + (size_t)e * IN_D * HID_D;
    const float* __restrict__ bias = b1 + (size_t)e * HID_D;
    const int ntile = blockIdx.x * TILE;

    __shared__ float As[BK][TILE];
    __shared__ float Bs[BK][TILE];

    const int tid = threadIdx.x;
    const int tx = tid & 15, ty = tid >> 4;
    const int tm0 = ty * 8, tn0 = tx * 8;

    const int arow = tid >> 1;
    const int akk = (tid & 1) * 8;
    const int tok = row_token[rtile + arow];
    const float* __restrict__ xrow = x + (size_t)tok * IN_D + akk;

    const int bkk = tid >> 4;
    const int bn = (tid & 15) * 8;
    const float* __restrict__ wrow = W + (size_t)bkk * HID_D + ntile + bn;

    float acc[8][8];
#pragma unroll
    for (int i = 0; i < 8; ++i)
#pragma unroll
        for (int j = 0; j < 8; ++j) acc[i][j] = 0.f;

    for (int k0 = 0; k0 < IN_D; k0 += BK) {
        float4 a0 = *(const float4*)(xrow + k0);
        float4 a1 = *(const float4*)(xrow + k0 + 4);
        float4 bv0 = *(const float4*)(wrow + (size_t)k0 * HID_D);
        float4 bv1 = *(const float4*)(wrow + (size_t)k0 * HID_D + 4);
        __syncthreads();
        As[akk + 0][arow] = a0.x; As[akk + 1][arow] = a0.y;
        As[akk + 2][arow] = a0.z; As[akk + 3][arow] = a0.w;
        As[akk + 4][arow] = a1.x; As[akk + 5][arow] = a1.y;
        As[akk + 6][arow] = a1.z; As[akk + 7][arow] = a1.w;
        *(float4*)&Bs[bkk][bn] = bv0;
        *(float4*)&Bs[bkk][bn + 4] = bv1;
        __syncthreads();
#pragma unroll
        for (int k = 0; k < BK; ++k) {
            float a_[8], b_[8];
            *(float4*)&a_[0] = *(const float4*)&As[k][tm0];
            *(float4*)&a_[4] = *(const float4*)&As[k][tm0 + 4];
            *(float4*)&b_[0] = *(const float4*)&Bs[k][tn0];
            *(float4*)&b_[4] = *(const float4*)&Bs[k][tn0 + 4];
#pragma unroll
            for (int i = 0; i < 8; ++i)
#pragma unroll
                for (int j = 0; j < 8; ++j) acc[i][j] = fmaf(a_[i], b_[j], acc[i][j]);
        }
    }

    float bb[8];
#pragma unroll
    for (int j = 0; j < 8; ++j) bb[j] = bias[ntile + tn0 + j];
#pragma unroll
    for (int i = 0; i < 8; ++i) {
        const int grow = rtile + tm0 + i;
        float* hp = hidden + (size_t)(grow - rbase) * HID_D + ntile + tn0;
        float o[8];
#pragma unroll
        for (int j = 0; j < 8; ++j) o[j] = gelu_exact(acc[i][j] + bb[j]);
        *(float4*)hp = make_float4(o[0], o[1], o[2], o[3]);
        *(float4*)(hp + 4) = make_float4(o[4], o[5], o[6], o[7]);
    }
}

__global__ __launch_bounds__(256)
void expert_gemm2(const float* __restrict__ hidden, const float* __restrict__ w2,
                  const float* __restrict__ b2, const int* __restrict__ ctrl,
                  const int* __restrict__ row_token, const float* __restrict__ row_w,
                  float* __restrict__ out, int rbase) {
    const int total = ctrl[CTRL_OFFS + NEXP];
    const int rtile = rbase + blockIdx.y * TILE;
    if (rtile >= total) return;
    int e = 0;
#pragma unroll
    for (int j = 1; j < NEXP; ++j) if (rtile >= ctrl[CTRL_OFFS + j]) e = j;

    const float* __restrict__ W = w2 + (size_t)e * HID_D * OUT_D;
    const float* __restrict__ bias = b2 + (size_t)e * OUT_D;
    const int ntile = blockIdx.x * TILE;

    __shared__ float As[BK][TILE];
    __shared__ float Bs[BK][TILE];

    const int tid = threadIdx.x;
    const int tx = tid & 15, ty = tid >> 4;
    const int tm0 = ty * 8, tn0 = tx * 8;

    const int arow = tid >> 1;
    const int akk = (tid & 1) * 8;
    const float* __restrict__ hrow =
        hidden + (size_t)(rtile - rbase + arow) * HID_D + akk;

    const int bkk = tid >> 4;
    const int bn = (tid & 15) * 8;
    const float* __restrict__ wrow = W + (size_t)bkk * OUT_D + ntile + bn;

    float acc[8][8];
#pragma unroll
    for (int i = 0; i < 8; ++i)
#pragma unroll
        for (int j = 0; j < 8; ++j) acc[i][j] = 0.f;

    for (int k0 = 0; k0 < HID_D; k0 += BK) {
        float4 a0 = *(const float4*)(hrow + k0);
        float4 a1 = *(const float4*)(hrow + k0 + 4);
        float4 bv0 = *(const float4*)(wrow + (size_t)k0 * OUT_D);
        float4 bv1 = *(const float4*)(wrow + (size_t)k0 * OUT_D + 4);
        __syncthreads();
        As[akk + 0][arow] = a0.x; As[akk + 1][arow] = a0.y;
        As[akk + 2][arow] = a0.z; As[akk + 3][arow] = a0.w;
        As[akk + 4][arow] = a1.x; As[akk + 5][arow] = a1.y;
        As[akk + 6][arow] = a1.z; As[akk + 7][arow] = a1.w;
        *(float4*)&Bs[bkk][bn] = bv0;
        *(float4*)&Bs[bkk][bn + 4] = bv1;
        __syncthreads();
#pragma unroll
        for (int k = 0; k < BK; ++k) {
            float a_[8], b_[8];
            *(float4*)&a_[0] = *(const float4*)&As[k][tm0];
            *(float4*)&a_[4] = *(const float4*)&As[k][tm0 + 4];
            *(float4*)&b_[0] = *(const float4*)&Bs[k][tn0];
            *(float4*)&b_[4] = *(const float4*)&Bs[k][tn0 + 4];
#pragma unroll
            for (int i = 0; i < 8; ++i)
#pragma unroll
                for (int j = 0; j < 8; ++j) acc[i][j] = fmaf(a_[i], b_[j], acc[i][j]);
        }
    }

    float bb[8];
#pragma unroll
    for (int j = 0; j < 8; ++j) bb[j] = bias[ntile + tn0 + j];
#pragma unroll
    for (int i = 0; i < 8; ++i) {
        const int grow = rtile + tm0 + i;
        const float wv = row_w[grow];
        if (wv != 0.f) {
            const int tok = row_token[grow];
            float* op = out + (size_t)tok * OUT_D + ntile + tn0;
#pragma unroll
            for (int j = 0; j < 8; ++j) atomicAdd(op + j, wv * (acc[i][j] + bb[j]));
        }
    }
}

// ---------------- host ----------------

extern "C" void kernel_launch(void* const* d_in, const int* in_sizes, int n_in,
                              void* d_out, int out_size, void* d_ws, size_t ws_size,
                              hipStream_t stream) {
    const float* x   = (const float*)d_in[0];
    const float* sig = (const float*)d_in[1];
    const float* tc  = (const float*)d_in[2];
    const float* rs  = (const float*)d_in[3];
    const float* rw1 = (const float*)d_in[4];
    const float* rb1 = (const float*)d_in[5];
    const float* rw2 = (const float*)d_in[6];
    const float* rb2 = (const float*)d_in[7];
    const float* ew1 = (const float*)d_in[8];
    const float* eb1 = (const float*)d_in[9];
    const float* ew2 = (const float*)d_in[10];
    const float* eb2 = (const float*)d_in[11];
    float* out = (float*)d_out;

    char* ws = (char*)d_ws;
    int* ctrl = (int*)ws;                                         // 4 KB
    int* tt_idx = (int*)(ws + 4096);                              // 64 KB
    float2* tt_w = (float2*)(ws + 69632);                         // 128 KB
    int* row_token = (int*)(ws + 200704);                         // 132 KB
    float* row_w = (float*)(ws + 335872);                         // 132 KB
    const size_t MAPS_END = 471040;

    // fp16 planes: x [B][IN], W1^T [e][HID][IN], W2^T [e][OUT][HID]
    const size_t XB = (size_t)B_TOK * IN_D * 2;                   // 32 MB
    const size_t W1B = (size_t)NEXP * IN_D * HID_D * 2;           // 64 MB
    const size_t W2B = (size_t)NEXP * HID_D * OUT_D * 2;          // 64 MB
    unsigned short* xf  = (unsigned short*)(ws + MAPS_END);
    unsigned short* w1f = (unsigned short*)(ws + MAPS_END + XB);
    unsigned short* w2f = (unsigned short*)(ws + MAPS_END + XB + W1B);
    const size_t FIX16 = MAPS_END + XB + W1B + W2B;               // ~160.9 MB

    const bool maps_ok = ws_size >= MAPS_END;
    const bool fp32_ok = ws_size >= MAPS_END + (size_t)TILE * HID_D * 4;
    const bool f16_ok  = ws_size >= FIX16 + (size_t)TILE * HID_D * 2;

    hipLaunchKernelGGL(zero_out_kernel, dim3(2048), dim3(256), 0, stream,
                       (float4*)out, B_TOK * OUT_D / 4);
    if (!maps_ok) return;

    hipLaunchKernelGGL(zero_ctrl_kernel, dim3(1), dim3(64), 0, stream, ctrl);
    hipLaunchKernelGGL(router_kernel, dim3(B_TOK / 4), dim3(256), 0, stream,
                       x, sig, tc, rs, rw1, rb1, rw2, rb2, ctrl, tt_idx, tt_w);
    hipLaunchKernelGGL(finalize_kernel, dim3(1), dim3(256), 0, stream,
                       ctrl, row_token, row_w);
    hipLaunchKernelGGL(scatter_kernel, dim3(B_TOK / 256), dim3(256), 0, stream,
                       tt_idx, tt_w, ctrl, row_token, row_w);

    if (f16_ok) {
        size_t avail = ws_size - FIX16;
        long long q = (long long)(avail / ((size_t)HID_D * 2));
        int qrows = (int)(q > ROWS_MAX ? ROWS_MAX : q);
        qrows &= ~(TILE - 1);   // f16_ok guarantees qrows >= TILE
        unsigned short* hid = (unsigned short*)(ws + FIX16);
        const int ngroups = (ROWS_MAX + qrows - 1) / qrows;

        hipLaunchKernelGGL(conv_x_f16, dim3(B_TOK * IN_D / 8 / 256), dim3(256),
                           0, stream, x, xf);
        hipLaunchKernelGGL(conv_w_f16, dim3(HID_D / 64, IN_D / 64, NEXP), dim3(256),
                           0, stream, ew1, w1f, IN_D, HID_D);
        hipLaunchKernelGGL(conv_w_f16, dim3(OUT_D / 64, HID_D / 64, NEXP), dim3(256),
                           0, stream, ew2, w2f, HID_D, OUT_D);

        const int ny = qrows / TILE;
        for (int g = 0; g < ngroups; ++g) {
            const int rbase = g * qrows;
            hipLaunchKernelGGL(mm1_f16, dim3(32 * ny), dim3(256), 0, stream,
                               xf, w1f, eb1, ctrl, row_token, hid, rbase);
            hipLaunchKernelGGL(mm2_f16, dim3(8 * ny), dim3(256), 0, stream,
                               hid, w2f, eb2, ctrl, row_token, row_w, out, rbase);
        }
    } else if (fp32_ok) {
        float* hidden = (float*)(ws + MAPS_END);
        size_t avail = ws_size - MAPS_END;
        long long q = (long long)(avail / ((size_t)HID_D * sizeof(float)));
        int qrows = (int)(q > ROWS_MAX ? ROWS_MAX : q);
        qrows &= ~(TILE - 1);
        const int ngroups = (ROWS_MAX + qrows - 1) / qrows;
        for (int g = 0; g < ngroups; ++g) {
            const int rbase = g * qrows;
            hipLaunchKernelGGL(expert_gemm1, dim3(HID_D / TILE, qrows / TILE), dim3(256),
                               0, stream, x, ew1, eb1, ctrl, row_token, hidden, rbase);
            hipLaunchKernelGGL(expert_gemm2, dim3(OUT_D / TILE, qrows / TILE), dim3(256),
                               0, stream, hidden, ew2, eb2, ctrl, row_token, row_w, out, rbase);
        }
    }
    // else: routing ran but no GEMM workspace — output stays zero (clean signal).
}